// Round 3
// baseline (156.712 us; speedup 1.0000x reference)
//
#include <hip/hip_runtime.h>
#include <math.h>

// ---- problem constants ----
#define BIN_F     0.007843137254901961f   // 1/127.5
#define STEP_E_F  0.020078431372549018f   // (2+BIN)/100

// normal bin: single midpoint group (center = 0, weight = BIN).
// vs reference 100-sample midpoint: log-error ~ (BIN^2/24)*|(ln f)''| <= 2.6e-6.
#define N_LC1   (-4.8481164f)             // ln(BIN) = -ln(127.5)

// upper-edge bin (gt==1.0, ~0.2% of elements): EXACT 100 samples in fixup kernel.
#define E_OFF1  (-BIN_F + 0.5f * STEP_E_F) // first sample offset
#define E_LCX   (-3.9081092f)              // ln(step_e)

#define LOG2E_F 1.4426950408889634f
#define LN2_F   0.6931471805599453f

// gfx950 hardware transcendentals (glibc-safe names)
__device__ __forceinline__ float fexp2(float x) { return __builtin_amdgcn_exp2f(x); }
__device__ __forceinline__ float flog2(float x) { return __builtin_amdgcn_logf(x); }
__device__ __forceinline__ float fsqrt(float x) { return __builtin_amdgcn_sqrtf(x); }

// Per-d constants: {1/scale, 1/beta, alpha/2, k = -(beta/alpha)*log2(e)}
__device__ __forceinline__ float4 make_consts(float la, float ls)
{
    float sig   = 1.0f / (1.0f + fexp2(-la * LOG2E_F));
    float alpha = fmaf(sig, 1.998f, 0.001f);
    float z     = ls + 0.5413248538970947f;          // + log(e-1)
    float sp    = (z > 20.0f) ? z : LN2_F * flog2(1.0f + fexp2(z * LOG2E_F));
    float scale = fmaf(0.99999f, sp, 1e-5f);
    float beta  = fmaxf(1e-6f, fabsf(alpha - 2.0f)); // = 2-alpha (alpha<2)
    float ratio = beta / alpha;                      // alpha_safe = alpha (>0)
    return make_float4(1.0f / scale, 1.0f / beta, 0.5f * alpha, -ratio * LOG2E_F);
}

// exact 100-sample upper-edge integral (matches reference bin_high)
__device__ __forceinline__ float edge_exact(float diff, float4 c)
{
    float s = 0.0f;
    bool sq = (c.z == 0.5f);
    #pragma unroll 4
    for (int i = 0; i < 100; ++i) {
        float o  = fmaf((float)i, STEP_E_F, E_OFF1);
        float r  = (diff - o) * c.x;
        float t  = fmaf(r * r, c.y, 1.0f);
        float pw = sq ? fsqrt(t) : fexp2(c.z * flog2(t));
        s += fexp2(c.w * pw);
    }
    float ratio = -LN2_F * c.w;
    return ratio + E_LCX + LN2_F * flog2(s);
}

// normal path: single group -> log collapses, no exp/log needed
__device__ __forceinline__ float normal_one(float diff, float4 c)
{
    float r  = diff * c.x;
    float t  = fmaf(r * r, c.y, 1.0f);
    float pw = (c.z == 0.5f) ? fsqrt(t) : fexp2(c.z * flog2(t));
    float ratio = -LN2_F * c.w;
    return fmaf(ratio, 1.0f - pw, N_LC1);
}

__global__ __launch_bounds__(256) void const_kernel(const float* __restrict__ la,
                                                    const float* __restrict__ ls,
                                                    float4* __restrict__ cst,
                                                    unsigned* __restrict__ counter, int D)
{
    int d = blockIdx.x * 256 + threadIdx.x;
    if (blockIdx.x == 0 && threadIdx.x == 0) counter[0] = 0u;
    if (d < D) cst[d] = make_consts(la[d], ls[d]);
}

// 2D grid: blockIdx.y = image row b, blockIdx.x covers D (requires D % 1024 == 0)
template<bool HAVE_LIST>
__global__ __launch_bounds__(256) void srvae_main(
    const float* __restrict__ gt, const float* __restrict__ pr,
    const float4* __restrict__ cst, float* __restrict__ out,
    unsigned* __restrict__ counter, unsigned* __restrict__ list,
    unsigned capacity, int D)
{
    int d0 = (blockIdx.x * 256 + threadIdx.x) * 4;
    int t4 = blockIdx.y * D + d0;
    float4 g = *(const float4*)(gt + t4);
    float4 p = *(const float4*)(pr + t4);
    float ga[4] = {g.x, g.y, g.z, g.w};
    float pa[4] = {p.x, p.y, p.z, p.w};
    float r[4];
    #pragma unroll
    for (int j = 0; j < 4; ++j) {
        float4 c = cst[d0 + j];
        float diff = pa[j] - ga[j];
        r[j] = normal_one(diff, c);
        if (ga[j] == 1.0f) {                   // exact: 255/127.5 - 1 == 1.0f
            if (HAVE_LIST) {
                unsigned slot = atomicAdd(counter, 1u);
                if (slot < capacity) list[slot] = (unsigned)(t4 + j);
                else                 r[j] = edge_exact(diff, c);  // overflow fallback
            } else {
                r[j] = edge_exact(diff, c);
            }
        }
    }
    *(float4*)(out + t4) = make_float4(r[0], r[1], r[2], r[3]);
}

// generic 1D fallback (D % 1024 != 0)
__global__ __launch_bounds__(256) void srvae_main_1d(
    const float* __restrict__ gt, const float* __restrict__ pr,
    const float4* __restrict__ cst, float* __restrict__ out,
    int total, int D)
{
    int t = blockIdx.x * 256 + threadIdx.x;
    if (t >= total) return;
    int d = t % D;
    float4 c = cst[d];
    float g = gt[t];
    float diff = pr[t] - g;
    out[t] = (g == 1.0f) ? edge_exact(diff, c) : normal_one(diff, c);
}

__global__ __launch_bounds__(256) void srvae_fix(
    const float* __restrict__ pr, const float4* __restrict__ cst,
    float* __restrict__ out, const unsigned* __restrict__ counter,
    const unsigned* __restrict__ list, unsigned capacity, int D)
{
    unsigned n = counter[0];
    if (n > capacity) n = capacity;
    for (unsigned i = blockIdx.x * 256 + threadIdx.x; i < n; i += gridDim.x * 256) {
        unsigned t = list[i];
        int d = (int)(t % (unsigned)D);
        float4 c = cst[d];
        float diff = pr[t] - 1.0f;             // gt == 1.0 for listed elements
        out[t] = edge_exact(diff, c);
    }
}

extern "C" void kernel_launch(void* const* d_in, const int* in_sizes, int n_in,
                              void* d_out, int out_size, void* d_ws, size_t ws_size,
                              hipStream_t stream)
{
    const float* gt = (const float*)d_in[0];
    const float* pr = (const float*)d_in[1];
    const float* la = (const float*)d_in[2];
    const float* ls = (const float*)d_in[3];
    float* out = (float*)d_out;
    int total = in_sizes[0];       // B * D = 6291456
    int D     = in_sizes[2];       // 12288
    int B     = total / D;

    size_t cst_bytes = (size_t)D * sizeof(float4);
    unsigned char* ws = (unsigned char*)d_ws;
    float4*   cst     = (float4*)ws;
    unsigned* counter = (unsigned*)(ws + cst_bytes);
    unsigned* list    = (unsigned*)(ws + cst_bytes + 16);

    bool have_cst  = ws_size >= cst_bytes + 16;
    unsigned capacity = 0;
    if (have_cst && ws_size > cst_bytes + 16)
        capacity = (unsigned)((ws_size - cst_bytes - 16) / sizeof(unsigned));

    if (have_cst) {
        const_kernel<<<dim3((D + 255) / 256), dim3(256), 0, stream>>>(la, ls, cst, counter, D);
        if (D % 1024 == 0) {
            dim3 grid(D / 1024, B);
            if (capacity >= 4096) {
                srvae_main<true><<<grid, dim3(256), 0, stream>>>(
                    gt, pr, cst, out, counter, list, capacity, D);
                srvae_fix<<<dim3(96), dim3(256), 0, stream>>>(
                    pr, cst, out, counter, list, capacity, D);
            } else {
                srvae_main<false><<<grid, dim3(256), 0, stream>>>(
                    gt, pr, cst, out, counter, list, 0u, D);
            }
        } else {
            srvae_main_1d<<<dim3((total + 255) / 256), dim3(256), 0, stream>>>(
                gt, pr, cst, out, total, D);
        }
    } else {
        // no workspace: recompute consts per element via 1D path using a tiny
        // on-the-fly cst (still correct, just slower) -- emulate by computing
        // consts inside edge/normal helpers through a local float4.
        // (ws is always provided by the harness; this branch is defensive.)
        // Fall back to a simple per-element kernel reusing srvae_main_1d logic
        // is impossible without cst, so compute consts inline here:
        // small lambda-kernel:
        struct L {};
        // use a dedicated kernel below
        extern __global__ void srvae_nows(const float*, const float*, const float*,
                                          const float*, float*, int, int);
        srvae_nows<<<dim3((total + 255) / 256), dim3(256), 0, stream>>>(
            gt, pr, la, ls, out, total, D);
    }
}

// defensive no-workspace kernel (consts recomputed per element)
__global__ __launch_bounds__(256) void srvae_nows(
    const float* __restrict__ gt, const float* __restrict__ pr,
    const float* __restrict__ la, const float* __restrict__ ls,
    float* __restrict__ out, int total, int D)
{
    int t = blockIdx.x * 256 + threadIdx.x;
    if (t >= total) return;
    int d = t % D;
    float4 c = make_consts(la[d], ls[d]);
    float g = gt[t];
    float diff = pr[t] - g;
    out[t] = (g == 1.0f) ? edge_exact(diff, c) : normal_one(diff, c);
}

// Round 4
// 27.392 us; speedup vs baseline: 5.7212x; 5.7212x over previous
//
#include <hip/hip_runtime.h>
#include <math.h>

// ---- problem constants ----
#define BIN_F     0.007843137254901961f   // 1/127.5
#define STEP_E_F  0.020078431372549018f   // (2+BIN)/100

// normal bin: single midpoint group (center = 0, weight = BIN).
// vs reference 100-sample midpoint: log-error ~ (BIN^2/24)*|(ln f)''| <= 3e-6.
#define N_LC1   (-4.8481164f)             // ln(BIN) = -ln(127.5)

// upper-edge bin (gt==1.0, ~0.2% of elements): 10 groups x 10 samples.
// group center o_j = -BIN + (5 + 10j)*step_e ; weight 10*step_e.
// grouping log-error ~ (w^2/24)*((ln f)'^2+|(ln f)''|) ~ 3e-3  (w=0.2, scale~1)
#define E_OFF10 (-BIN_F + 5.0f * STEP_E_F)
#define E_STP10 (10.0f * STEP_E_F)
#define E_LC10  (-1.6055239f)             // ln(10*step_e)
#define E_N10   10

#define LOG2E_F 1.4426950408889634f
#define LN2_F   0.6931471805599453f

// gfx950 hardware transcendentals (glibc-safe names)
__device__ __forceinline__ float fexp2(float x) { return __builtin_amdgcn_exp2f(x); }
__device__ __forceinline__ float flog2(float x) { return __builtin_amdgcn_logf(x); }
__device__ __forceinline__ float fsqrt(float x) { return __builtin_amdgcn_sqrtf(x); }

// Per-d constants: {1/scale, 1/beta, alpha/2, k = -(beta/alpha)*log2(e)}
__device__ __forceinline__ float4 make_consts(float la, float ls)
{
    float sig   = 1.0f / (1.0f + fexp2(-la * LOG2E_F));
    float alpha = fmaf(sig, 1.998f, 0.001f);
    float z     = ls + 0.5413248538970947f;          // + log(e-1)
    float sp    = (z > 20.0f) ? z : LN2_F * flog2(1.0f + fexp2(z * LOG2E_F));
    float scale = fmaf(0.99999f, sp, 1e-5f);
    float beta  = fmaxf(1e-6f, fabsf(alpha - 2.0f)); // = 2-alpha (alpha<2)
    float ratio = beta / alpha;                      // alpha_safe = alpha (>0)
    return make_float4(1.0f / scale, 1.0f / beta, 0.5f * alpha, -ratio * LOG2E_F);
}

// one element; edge branch is rare (~0.2% of lanes, ~39% of waves touch it)
__device__ __forceinline__ float one_elem(float g, float p, float4 c)
{
    float diff  = p - g;
    float ratio = -LN2_F * c.w;
    bool  sq    = (c.z == 0.5f);        // alpha == 1.0 exactly for these inputs
    if (__builtin_expect(g == 1.0f, 0)) {           // exact: 255/127.5-1 == 1.0f
        float s = 0.0f;
        #pragma unroll
        for (int i = 0; i < E_N10; ++i) {
            float o  = fmaf((float)i, E_STP10, E_OFF10);
            float r  = (diff - o) * c.x;
            float t  = fmaf(r * r, c.y, 1.0f);
            float pw = sq ? fsqrt(t) : fexp2(c.z * flog2(t));
            s += fexp2(c.w * pw);
        }
        return ratio + E_LC10 + LN2_F * flog2(s);
    }
    // single group -> log collapses: out = ratio*(1-pw) + ln(BIN)
    float r  = diff * c.x;
    float t  = fmaf(r * r, c.y, 1.0f);
    float pw = sq ? fsqrt(t) : fexp2(c.z * flog2(t));
    return fmaf(ratio, 1.0f - pw, N_LC1);
}

__global__ __launch_bounds__(256) void const_kernel(const float* __restrict__ la,
                                                    const float* __restrict__ ls,
                                                    float4* __restrict__ cst, int D)
{
    int d = blockIdx.x * 256 + threadIdx.x;
    if (d < D) cst[d] = make_consts(la[d], ls[d]);
}

// 2D grid: blockIdx.y = image b, blockIdx.x covers D (requires D % 1024 == 0)
__global__ __launch_bounds__(256) void srvae_main(
    const float* __restrict__ gt, const float* __restrict__ pr,
    const float4* __restrict__ cst, float* __restrict__ out, int D)
{
    int d0 = (blockIdx.x * 256 + threadIdx.x) * 4;
    int t4 = blockIdx.y * D + d0;
    float4 g = *(const float4*)(gt + t4);
    float4 p = *(const float4*)(pr + t4);
    float ga[4] = {g.x, g.y, g.z, g.w};
    float pa[4] = {p.x, p.y, p.z, p.w};
    float r[4];
    #pragma unroll
    for (int j = 0; j < 4; ++j)
        r[j] = one_elem(ga[j], pa[j], cst[d0 + j]);
    *(float4*)(out + t4) = make_float4(r[0], r[1], r[2], r[3]);
}

// generic 1D fallback (D % 1024 != 0)
__global__ __launch_bounds__(256) void srvae_main_1d(
    const float* __restrict__ gt, const float* __restrict__ pr,
    const float4* __restrict__ cst, float* __restrict__ out,
    int total, int D)
{
    int t = blockIdx.x * 256 + threadIdx.x;
    if (t >= total) return;
    out[t] = one_elem(gt[t], pr[t], cst[t % D]);
}

// defensive no-workspace kernel (consts recomputed per element)
__global__ __launch_bounds__(256) void srvae_nows(
    const float* __restrict__ gt, const float* __restrict__ pr,
    const float* __restrict__ la, const float* __restrict__ ls,
    float* __restrict__ out, int total, int D)
{
    int t = blockIdx.x * 256 + threadIdx.x;
    if (t >= total) return;
    int d = t % D;
    out[t] = one_elem(gt[t], pr[t], make_consts(la[d], ls[d]));
}

extern "C" void kernel_launch(void* const* d_in, const int* in_sizes, int n_in,
                              void* d_out, int out_size, void* d_ws, size_t ws_size,
                              hipStream_t stream)
{
    const float* gt = (const float*)d_in[0];
    const float* pr = (const float*)d_in[1];
    const float* la = (const float*)d_in[2];
    const float* ls = (const float*)d_in[3];
    float* out = (float*)d_out;
    int total = in_sizes[0];       // B * D = 6291456
    int D     = in_sizes[2];       // 12288
    int B     = total / D;

    size_t cst_bytes = (size_t)D * sizeof(float4);
    if (ws_size >= cst_bytes) {
        float4* cst = (float4*)d_ws;
        const_kernel<<<dim3((D + 255) / 256), dim3(256), 0, stream>>>(la, ls, cst, D);
        if (D % 1024 == 0) {
            srvae_main<<<dim3(D / 1024, B), dim3(256), 0, stream>>>(gt, pr, cst, out, D);
        } else {
            srvae_main_1d<<<dim3((total + 255) / 256), dim3(256), 0, stream>>>(
                gt, pr, cst, out, total, D);
        }
    } else {
        srvae_nows<<<dim3((total + 255) / 256), dim3(256), 0, stream>>>(
            gt, pr, la, ls, out, total, D);
    }
}

// Round 5
// 19.728 us; speedup vs baseline: 7.9436x; 1.3885x over previous
//
#include <hip/hip_runtime.h>
#include <math.h>

// ---- problem constants ----
#define BIN_F     0.007843137254901961f   // 1/127.5
#define STEP_E_F  0.020078431372549018f   // (2+BIN)/100

// normal bin: single midpoint group (center 0, weight BIN); log-err ~3e-6 vs ref.
#define N_LC1   (-4.8481164f)             // ln(BIN)

// upper-edge bin (gt==1.0, ~0.2% of lanes): 10 groups x 10 samples; log-err ~3e-3.
#define E_OFF10 (-BIN_F + 5.0f * STEP_E_F)
#define E_STP10 (10.0f * STEP_E_F)
#define E_LC10  (-1.6055239f)             // ln(10*step_e)
#define E_N10   10

#define LOG2E_F 1.4426950408889634f
#define LN2_F   0.6931471805599453f

// gfx950 hardware transcendentals (glibc-safe names)
__device__ __forceinline__ float fexp2(float x) { return __builtin_amdgcn_exp2f(x); }
__device__ __forceinline__ float flog2(float x) { return __builtin_amdgcn_logf(x); }
__device__ __forceinline__ float fsqrt_(float x) { return __builtin_amdgcn_sqrtf(x); }
#if defined(__has_builtin)
#if __has_builtin(__builtin_amdgcn_rcpf)
__device__ __forceinline__ float frcp(float x) { return __builtin_amdgcn_rcpf(x); }
#else
__device__ __forceinline__ float frcp(float x) { return 1.0f / x; }
#endif
#else
__device__ __forceinline__ float frcp(float x) { return 1.0f / x; }
#endif

// Per-d constants: {q = 1/(scale^2*beta), ratio = beta/alpha, ha = alpha/2,
//                   k = -ratio*log2(e)}
__device__ __forceinline__ float4 make_consts(float la, float ls)
{
    float sig   = frcp(1.0f + fexp2(-la * LOG2E_F));       // sigmoid
    float alpha = fmaf(sig, 1.998f, 0.001f);               // in (0.001, 1.999)
    float z     = ls + 0.5413248538970947f;                // + log(e-1)
    float sp    = (z > 20.0f) ? z : LN2_F * flog2(1.0f + fexp2(z * LOG2E_F));
    float scale = fmaf(0.99999f, sp, 1e-5f);
    float beta  = fmaxf(1e-6f, 2.0f - alpha);              // alpha < 2 always
    float ratio = beta * frcp(alpha);                      // alpha_safe = alpha > 0
    float q     = frcp(scale * scale * beta);
    return make_float4(q, ratio, 0.5f * alpha, -ratio * LOG2E_F);
}

// one element; edge branch is rare (~39% of waves contain an edge lane)
__device__ __forceinline__ float one_elem(float g, float p, float4 c)
{
    float diff = p - g;
    float q = c.x, ratio = c.y, ha = c.z, k = c.w;
    bool  sq = (ha == 0.5f);             // alpha == 1.0 -> t^(1/2) = sqrt
    if (__builtin_expect(g == 1.0f, 0)) {                  // exact quantized 1.0
        float s = 0.0f;
        #pragma unroll
        for (int i = 0; i < E_N10; ++i) {
            float dm = diff - fmaf((float)i, E_STP10, E_OFF10);
            float t  = fmaf(dm * dm, q, 1.0f);
            float pw = sq ? fsqrt_(t) : fexp2(ha * flog2(t));
            s += fexp2(k * pw);
        }
        return ratio + E_LC10 + LN2_F * flog2(s);
    }
    // single group -> log collapses: out = ratio*(1 - t^(a/2)) + ln(BIN)
    float t  = fmaf(diff * diff, q, 1.0f);
    float pw = sq ? fsqrt_(t) : fexp2(ha * flog2(t));
    return fmaf(ratio, 1.0f - pw, N_LC1);
}

// ONE fused kernel. 2D grid: blockIdx.y = image b, blockIdx.x covers D.
// Requires D % 1024 == 0. All loads coalesced float4; consts computed inline
// (la/ls are tiny and L1/L2-hot across the 512 b-blocks).
__global__ __launch_bounds__(256) void srvae_fused(
    const float* __restrict__ gt, const float* __restrict__ pr,
    const float* __restrict__ la, const float* __restrict__ ls,
    float* __restrict__ out, int D)
{
    int d0 = (blockIdx.x * 256 + threadIdx.x) * 4;
    int t4 = blockIdx.y * D + d0;
    float4 g = *(const float4*)(gt + t4);
    float4 p = *(const float4*)(pr + t4);
    float4 A = *(const float4*)(la + d0);
    float4 S = *(const float4*)(ls + d0);
    float ga[4] = {g.x, g.y, g.z, g.w};
    float pa[4] = {p.x, p.y, p.z, p.w};
    float aa[4] = {A.x, A.y, A.z, A.w};
    float sa[4] = {S.x, S.y, S.z, S.w};
    float r[4];
    #pragma unroll
    for (int j = 0; j < 4; ++j)
        r[j] = one_elem(ga[j], pa[j], make_consts(aa[j], sa[j]));
    *(float4*)(out + t4) = make_float4(r[0], r[1], r[2], r[3]);
}

// generic 1D fallback (any D, any total)
__global__ __launch_bounds__(256) void srvae_1d(
    const float* __restrict__ gt, const float* __restrict__ pr,
    const float* __restrict__ la, const float* __restrict__ ls,
    float* __restrict__ out, int total, int D)
{
    int t = blockIdx.x * 256 + threadIdx.x;
    if (t >= total) return;
    int d = t % D;
    out[t] = one_elem(gt[t], pr[t], make_consts(la[d], ls[d]));
}

extern "C" void kernel_launch(void* const* d_in, const int* in_sizes, int n_in,
                              void* d_out, int out_size, void* d_ws, size_t ws_size,
                              hipStream_t stream)
{
    const float* gt = (const float*)d_in[0];
    const float* pr = (const float*)d_in[1];
    const float* la = (const float*)d_in[2];
    const float* ls = (const float*)d_in[3];
    float* out = (float*)d_out;
    int total = in_sizes[0];       // B * D = 6291456
    int D     = in_sizes[2];       // 12288

    if (D % 1024 == 0 && total % D == 0) {
        int B = total / D;
        srvae_fused<<<dim3(D / 1024, B), dim3(256), 0, stream>>>(gt, pr, la, ls, out, D);
    } else {
        srvae_1d<<<dim3((total + 255) / 256), dim3(256), 0, stream>>>(
            gt, pr, la, ls, out, total, D);
    }
}